// Round 1
// baseline (646.908 us; speedup 1.0000x reference)
//
#include <hip/hip_runtime.h>

#define LDS_AS __attribute__((address_space(3)))
#define GLB_AS __attribute__((address_space(1)))

typedef __attribute__((ext_vector_type(8))) short bf16x8;   // 8 bf16 = 4 VGPRs (A/B frag)
typedef __attribute__((ext_vector_type(4))) float f32x4;    // C/D frag

static constexpr int NH = 4;
static constexpr int T  = 2048;
static constexpr int N  = 8192;
static constexpr int D  = 256;

__device__ inline unsigned short f2bf(float f) {
    unsigned int u = __float_as_uint(f);
    u += 0x7FFFu + ((u >> 16) & 1u);   // round-to-nearest-even
    return (unsigned short)(u >> 16);
}

__device__ inline void gl2lds16(const void* g, void* l) {
    __builtin_amdgcn_global_load_lds((GLB_AS void*)g, (LDS_AS void*)l, 16, 0, 0);
}

// ---------------- RoPE + bf16 cast: QR[h][t][n] ----------------
// freq(n) = 2^(-(n&~1)/512) / (2pi); ang = frac(t*freq) (in revolutions)
__global__ void rope_kernel(const float* __restrict__ Q, unsigned short* __restrict__ QR) {
    int g = blockIdx.x * 256 + threadIdx.x;     // one thread = 4 consecutive elements
    int base = g << 2;
    int n = base & (N - 1);
    int t = (base >> 13) & (T - 1);
    const float4 q = *(const float4*)(Q + (size_t)base);
    float tf = (float)t;
    const float inv2pi = 0.15915494309189535f;
    float f0 = exp2f((float)n       * (-1.0f / 512.0f)) * inv2pi;
    float f1 = exp2f((float)(n + 2) * (-1.0f / 512.0f)) * inv2pi;
    float r0 = tf * f0; r0 -= floorf(r0);
    float r1 = tf * f1; r1 -= floorf(r1);
    float s0 = __builtin_amdgcn_sinf(r0), c0 = __builtin_amdgcn_cosf(r0);
    float s1 = __builtin_amdgcn_sinf(r1), c1 = __builtin_amdgcn_cosf(r1);
    ushort4 o;
    o.x = f2bf(q.x * c0 - q.y * s0);
    o.y = f2bf(q.y * c0 + q.x * s0);
    o.z = f2bf(q.z * c1 - q.w * s1);
    o.w = f2bf(q.w * c1 + q.z * s1);
    *(ushort4*)(QR + (size_t)base) = o;
}

// ---------------- V -> Vt bf16 transpose: Vt[d][t] = bf16(V[t][d]) ----------------
__global__ void vt_kernel(const float* __restrict__ V, unsigned short* __restrict__ Vt) {
    int g = blockIdx.x * 256 + threadIdx.x;     // 0 .. T*D-1
    int t = g >> 8;          // D = 256
    int d = g & (D - 1);
    Vt[(size_t)d * T + t] = f2bf(V[g]);
}

// ---------------- GEMM1: S[h] = mask(QR[h] @ QR[h]^T), bf16 out ----------------
// 128x128 C-tile per block; 256 threads = 4 waves (2x2); each wave 64x64 = 4x4 MFMA frags.
// Only lower-triangle block pairs (bi >= bj) are launched.
__global__ __launch_bounds__(256) void gemm1_kernel(const unsigned short* __restrict__ QR,
                                                    unsigned short* __restrict__ S) {
    __shared__ __align__(16) unsigned short As[128 * 32];
    __shared__ __align__(16) unsigned short Bs[128 * 32];

    int bx = blockIdx.x;
    int h = bx / 136, pair = bx % 136;
    int bi = 0;
    while (((bi + 1) * (bi + 2)) / 2 <= pair) bi++;
    int bj = pair - (bi * (bi + 1)) / 2;

    const unsigned short* A = QR + (size_t)h * T * N + (size_t)bi * 128 * N;
    const unsigned short* B = QR + (size_t)h * T * N + (size_t)bj * 128 * N;

    int tid = threadIdx.x;
    int lane = tid & 63, wave = tid >> 6;
    int wm = wave >> 1, wn = wave & 1;
    int quad = lane >> 4, l16 = lane & 15;
    int srow = tid >> 2;             // staging: 4 threads per row, 8 bf16 each
    int scol = (tid & 3) * 8;

    f32x4 acc[4][4];
    #pragma unroll
    for (int i = 0; i < 4; i++)
        #pragma unroll
        for (int j = 0; j < 4; j++)
            #pragma unroll
            for (int r = 0; r < 4; r++) acc[i][j][r] = 0.0f;

    for (int k0 = 0; k0 < N; k0 += 32) {
        __syncthreads();   // previous ds_reads done before LDS overwrite
        gl2lds16(A + (size_t)srow * N + k0 + scol,        &As[srow * 32 + scol]);
        gl2lds16(A + (size_t)(srow + 64) * N + k0 + scol, &As[(srow + 64) * 32 + scol]);
        gl2lds16(B + (size_t)srow * N + k0 + scol,        &Bs[srow * 32 + scol]);
        gl2lds16(B + (size_t)(srow + 64) * N + k0 + scol, &Bs[(srow + 64) * 32 + scol]);
        __syncthreads();   // vmcnt(0) drain: staging complete

        bf16x8 a[4], b[4];
        #pragma unroll
        for (int i = 0; i < 4; i++) {
            int ra = wm * 64 + i * 16 + l16;
            a[i] = *(const bf16x8*)&As[ra * 32 + quad * 8];
            int rb = wn * 64 + i * 16 + l16;
            b[i] = *(const bf16x8*)&Bs[rb * 32 + quad * 8];
        }
        #pragma unroll
        for (int i = 0; i < 4; i++)
            #pragma unroll
            for (int j = 0; j < 4; j++)
                acc[i][j] = __builtin_amdgcn_mfma_f32_16x16x32_bf16(a[i], b[j], acc[i][j], 0, 0, 0);
    }

    // epilogue: C/D layout col = lane&15, row = quad*4 + r; strictly-lower mask s < t
    unsigned short* Sh = S + (size_t)h * T * T;
    #pragma unroll
    for (int i = 0; i < 4; i++) {
        int t_base = bi * 128 + wm * 64 + i * 16 + quad * 4;
        #pragma unroll
        for (int j = 0; j < 4; j++) {
            int s_g = bj * 128 + wn * 64 + j * 16 + l16;
            #pragma unroll
            for (int r = 0; r < 4; r++) {
                int t_g = t_base + r;
                float v = (s_g < t_g) ? acc[i][j][r] : 0.0f;
                Sh[(size_t)t_g * T + s_g] = f2bf(v);
            }
        }
    }
}

// ---------------- GEMM2: out[h] = S[h] @ Vt^T (Vt is D x T, bf16) ----------------
__global__ __launch_bounds__(256) void gemm2_kernel(const unsigned short* __restrict__ S,
                                                    const unsigned short* __restrict__ Vt,
                                                    float* __restrict__ out) {
    __shared__ __align__(16) unsigned short As[128 * 32];
    __shared__ __align__(16) unsigned short Bs[128 * 32];

    int bx = blockIdx.x;
    int h = bx >> 5;
    int rem = bx & 31;
    int bi = rem >> 1;         // t-block 0..15
    int dblk = rem & 1;        // d-block 0..1

    const unsigned short* A = S + (size_t)h * T * T + (size_t)bi * 128 * T;
    const unsigned short* B = Vt + (size_t)dblk * 128 * T;

    int tid = threadIdx.x;
    int lane = tid & 63, wave = tid >> 6;
    int wm = wave >> 1, wn = wave & 1;
    int quad = lane >> 4, l16 = lane & 15;
    int srow = tid >> 2;
    int scol = (tid & 3) * 8;

    f32x4 acc[4][4];
    #pragma unroll
    for (int i = 0; i < 4; i++)
        #pragma unroll
        for (int j = 0; j < 4; j++)
            #pragma unroll
            for (int r = 0; r < 4; r++) acc[i][j][r] = 0.0f;

    int kend = (bi + 1) * 128;   // causal: only s <= bi*128+127 contribute
    for (int k0 = 0; k0 < kend; k0 += 32) {
        __syncthreads();
        gl2lds16(A + (size_t)srow * T + k0 + scol,        &As[srow * 32 + scol]);
        gl2lds16(A + (size_t)(srow + 64) * T + k0 + scol, &As[(srow + 64) * 32 + scol]);
        gl2lds16(B + (size_t)srow * T + k0 + scol,        &Bs[srow * 32 + scol]);
        gl2lds16(B + (size_t)(srow + 64) * T + k0 + scol, &Bs[(srow + 64) * 32 + scol]);
        __syncthreads();

        bf16x8 a[4], b[4];
        #pragma unroll
        for (int i = 0; i < 4; i++) {
            int ra = wm * 64 + i * 16 + l16;
            a[i] = *(const bf16x8*)&As[ra * 32 + quad * 8];
            int rb = wn * 64 + i * 16 + l16;
            b[i] = *(const bf16x8*)&Bs[rb * 32 + quad * 8];
        }
        #pragma unroll
        for (int i = 0; i < 4; i++)
            #pragma unroll
            for (int j = 0; j < 4; j++)
                acc[i][j] = __builtin_amdgcn_mfma_f32_16x16x32_bf16(a[i], b[j], acc[i][j], 0, 0, 0);
    }

    float* oh = out + (size_t)h * T * D;
    #pragma unroll
    for (int i = 0; i < 4; i++) {
        int t_base = bi * 128 + wm * 64 + i * 16 + quad * 4;
        #pragma unroll
        for (int j = 0; j < 4; j++) {
            int d_g = dblk * 128 + wn * 64 + j * 16 + l16;
            #pragma unroll
            for (int r = 0; r < 4; r++) {
                int t_g = t_base + r;
                oh[(size_t)t_g * D + d_g] = acc[i][j][r];
            }
        }
    }
}

extern "C" void kernel_launch(void* const* d_in, const int* in_sizes, int n_in,
                              void* d_out, int out_size, void* d_ws, size_t ws_size,
                              hipStream_t stream) {
    const float* Q = (const float*)d_in[0];   // (1, 4, 2048, 8192) fp32
    const float* V = (const float*)d_in[1];   // (1, 1, 2048, 256)  fp32
    float* out = (float*)d_out;               // (1, 4, 2048, 256)  fp32

    // workspace layout (bf16 = 2B):
    //   QR: NH*T*N        = 134,217,728 B
    //   Vt: D*T           =   1,048,576 B
    //   S : NH*T*T        =  33,554,432 B
    const size_t qr_elems = (size_t)NH * T * N;
    const size_t vt_elems = (size_t)D * T;
    const size_t s_elems  = (size_t)NH * T * T;
    const size_t needed = (qr_elems + vt_elems + s_elems) * sizeof(unsigned short);
    if (ws_size < needed) return;  // workspace too small: bail without corrupting memory

    unsigned short* QR = (unsigned short*)d_ws;
    unsigned short* Vt = QR + qr_elems;
    unsigned short* S  = Vt + vt_elems;

    rope_kernel<<<(NH * T * N / 4) / 256, 256, 0, stream>>>(Q, QR);
    vt_kernel<<<(T * D) / 256, 256, 0, stream>>>(V, Vt);
    gemm1_kernel<<<NH * 136, 256, 0, stream>>>(QR, S);
    gemm2_kernel<<<NH * 32, 256, 0, stream>>>(S, Vt, out);
}

// Round 2
// 622.461 us; speedup vs baseline: 1.0393x; 1.0393x over previous
//
#include <hip/hip_runtime.h>

#define LDS_AS __attribute__((address_space(3)))
#define GLB_AS __attribute__((address_space(1)))

typedef __attribute__((ext_vector_type(8))) short bf16x8;   // 8 bf16 = 4 VGPRs (A/B frag)
typedef __attribute__((ext_vector_type(4))) float f32x4;    // C/D frag

static constexpr int NH = 4;
static constexpr int T  = 2048;
static constexpr int N  = 8192;
static constexpr int D  = 256;

__device__ inline unsigned short f2bf(float f) {
    unsigned int u = __float_as_uint(f);
    u += 0x7FFFu + ((u >> 16) & 1u);   // round-to-nearest-even
    return (unsigned short)(u >> 16);
}

__device__ inline void gl2lds16(const void* g, void* l) {
    __builtin_amdgcn_global_load_lds((GLB_AS void*)g, (LDS_AS void*)l, 16, 0, 0);
}

// ---------------- RoPE + bf16 cast: QR[h][t][n] ----------------
__global__ void rope_kernel(const float* __restrict__ Q, unsigned short* __restrict__ QR) {
    int g = blockIdx.x * 256 + threadIdx.x;     // one thread = 4 consecutive elements
    int base = g << 2;
    int n = base & (N - 1);
    int t = (base >> 13) & (T - 1);
    const float4 q = *(const float4*)(Q + (size_t)base);
    float tf = (float)t;
    const float inv2pi = 0.15915494309189535f;
    float f0 = exp2f((float)n       * (-1.0f / 512.0f)) * inv2pi;
    float f1 = exp2f((float)(n + 2) * (-1.0f / 512.0f)) * inv2pi;
    float r0 = tf * f0; r0 -= floorf(r0);
    float r1 = tf * f1; r1 -= floorf(r1);
    float s0 = __builtin_amdgcn_sinf(r0), c0 = __builtin_amdgcn_cosf(r0);
    float s1 = __builtin_amdgcn_sinf(r1), c1 = __builtin_amdgcn_cosf(r1);
    ushort4 o;
    o.x = f2bf(q.x * c0 - q.y * s0);
    o.y = f2bf(q.y * c0 + q.x * s0);
    o.z = f2bf(q.z * c1 - q.w * s1);
    o.w = f2bf(q.w * c1 + q.z * s1);
    *(ushort4*)(QR + (size_t)base) = o;
}

// ---------------- V -> Vt bf16 transpose via LDS: Vt[d][t] = bf16(V[t][d]) ----------------
// 64x64 tiles; coalesced reads (d-contiguous) and writes (t-contiguous).
__global__ void vt_kernel(const float* __restrict__ V, unsigned short* __restrict__ Vt) {
    __shared__ unsigned short tile[64 * 65];
    int tb = blockIdx.x >> 2, db = blockIdx.x & 3;
    int t0 = tb * 64, d0 = db * 64;
    int tid = threadIdx.x;
    #pragma unroll
    for (int r = 0; r < 16; r++) {
        int idx = tid + r * 256;           // 0..4095
        int tl = idx >> 6, dl = idx & 63;
        tile[tl * 65 + dl] = f2bf(V[(size_t)(t0 + tl) * D + d0 + dl]);
    }
    __syncthreads();
    #pragma unroll
    for (int r = 0; r < 16; r++) {
        int idx = tid + r * 256;
        int dl = idx >> 6, tl = idx & 63;
        Vt[(size_t)(d0 + dl) * T + t0 + tl] = tile[tl * 65 + dl];
    }
}

// ---------------- GEMM1: S[ks][h] = mask(QR[h][:, ksK:(ks+1)K] @ QR[h][:, same]^T) ----------------
// 128x128 C-tile, 4 waves (2x2), 4x4 MFMA frags/wave. Lower-triangle pairs only.
__global__ __launch_bounds__(256) void gemm1_kernel(const unsigned short* __restrict__ QR,
                                                    unsigned short* __restrict__ S, int KS) {
    __shared__ __align__(16) unsigned short As[128 * 32];
    __shared__ __align__(16) unsigned short Bs[128 * 32];

    int bx = blockIdx.x;
    int per_h = 136 * KS;
    int h = bx / per_h;
    int rem = bx % per_h;
    int pair = rem / KS;
    int ks = rem % KS;
    int bi = 0;
    while (((bi + 1) * (bi + 2)) / 2 <= pair) bi++;
    int bj = pair - (bi * (bi + 1)) / 2;

    const unsigned short* A = QR + (size_t)h * T * N + (size_t)bi * 128 * N;
    const unsigned short* B = QR + (size_t)h * T * N + (size_t)bj * 128 * N;

    int KN = N / KS;
    int k_begin = ks * KN, k_end = k_begin + KN;

    int tid = threadIdx.x;
    int lane = tid & 63, wave = tid >> 6;
    int wm = wave >> 1, wn = wave & 1;
    int quad = lane >> 4, l16 = lane & 15;
    int srow = tid >> 2;
    int scol = (tid & 3) * 8;

    f32x4 acc[4][4];
    #pragma unroll
    for (int i = 0; i < 4; i++)
        #pragma unroll
        for (int j = 0; j < 4; j++)
            #pragma unroll
            for (int r = 0; r < 4; r++) acc[i][j][r] = 0.0f;

    for (int k0 = k_begin; k0 < k_end; k0 += 32) {
        __syncthreads();
        gl2lds16(A + (size_t)srow * N + k0 + scol,        &As[srow * 32 + scol]);
        gl2lds16(A + (size_t)(srow + 64) * N + k0 + scol, &As[(srow + 64) * 32 + scol]);
        gl2lds16(B + (size_t)srow * N + k0 + scol,        &Bs[srow * 32 + scol]);
        gl2lds16(B + (size_t)(srow + 64) * N + k0 + scol, &Bs[(srow + 64) * 32 + scol]);
        __syncthreads();

        bf16x8 a[4], b[4];
        #pragma unroll
        for (int i = 0; i < 4; i++) {
            a[i] = *(const bf16x8*)&As[(wm * 64 + i * 16 + l16) * 32 + quad * 8];
            b[i] = *(const bf16x8*)&Bs[(wn * 64 + i * 16 + l16) * 32 + quad * 8];
        }
        #pragma unroll
        for (int i = 0; i < 4; i++)
            #pragma unroll
            for (int j = 0; j < 4; j++)
                acc[i][j] = __builtin_amdgcn_mfma_f32_16x16x32_bf16(a[i], b[j], acc[i][j], 0, 0, 0);
    }

    // epilogue: C/D layout col = lane&15, row = quad*4 + r; strictly-lower mask s < t
    unsigned short* Sh = S + (size_t)ks * NH * T * T + (size_t)h * T * T;
    #pragma unroll
    for (int i = 0; i < 4; i++) {
        int t_base = bi * 128 + wm * 64 + i * 16 + quad * 4;
        #pragma unroll
        for (int j = 0; j < 4; j++) {
            int s_g = bj * 128 + wn * 64 + j * 16 + l16;
            #pragma unroll
            for (int r = 0; r < 4; r++) {
                int t_g = t_base + r;
                float v = (s_g < t_g) ? acc[i][j][r] : 0.0f;
                Sh[(size_t)t_g * T + s_g] = f2bf(v);
            }
        }
    }
}

// ---------------- GEMM2: out[h] += S[ks][h][tile] @ Vt^T over <=512-wide K chunks ----------------
// grid = NH * 2(dblk) * KS * 40(chunk tasks); fp32 atomics into zeroed d_out.
__global__ __launch_bounds__(256) void gemm2_kernel(const unsigned short* __restrict__ S,
                                                    const unsigned short* __restrict__ Vt,
                                                    float* __restrict__ out, int KS) {
    __shared__ __align__(16) unsigned short As[128 * 32];
    __shared__ __align__(16) unsigned short Bs[128 * 32];

    int bx = blockIdx.x;
    int per_h = 2 * KS * 40;
    int h = bx / per_h;
    int rem = bx % per_h;
    int dblk = rem / (KS * 40);
    int rem2 = rem % (KS * 40);
    int ks = rem2 / 40;
    int tc = rem2 % 40;
    // decode (bi, chunk): nc(bi) = ceil((bi+1)/4), sum = 40
    int bi = 0, cum = 0;
    for (; bi < 16; bi++) { int nc = (bi + 4) >> 2; if (cum + nc > tc) break; cum += nc; }
    int c = tc - cum;

    int kend = (bi + 1) * 128;
    int cstart = c * 512;
    int clen = min(512, kend - cstart);   // multiple of 128

    const unsigned short* A = S + (size_t)ks * NH * T * T + (size_t)h * T * T
                                + (size_t)bi * 128 * T + cstart;
    const unsigned short* B = Vt + (size_t)dblk * 128 * T + cstart;

    int tid = threadIdx.x;
    int lane = tid & 63, wave = tid >> 6;
    int wm = wave >> 1, wn = wave & 1;
    int quad = lane >> 4, l16 = lane & 15;
    int srow = tid >> 2;
    int scol = (tid & 3) * 8;

    f32x4 acc[4][4];
    #pragma unroll
    for (int i = 0; i < 4; i++)
        #pragma unroll
        for (int j = 0; j < 4; j++)
            #pragma unroll
            for (int r = 0; r < 4; r++) acc[i][j][r] = 0.0f;

    for (int k0 = 0; k0 < clen; k0 += 32) {
        __syncthreads();
        gl2lds16(A + (size_t)srow * T + k0 + scol,        &As[srow * 32 + scol]);
        gl2lds16(A + (size_t)(srow + 64) * T + k0 + scol, &As[(srow + 64) * 32 + scol]);
        gl2lds16(B + (size_t)srow * T + k0 + scol,        &Bs[srow * 32 + scol]);
        gl2lds16(B + (size_t)(srow + 64) * T + k0 + scol, &Bs[(srow + 64) * 32 + scol]);
        __syncthreads();

        bf16x8 a[4], b[4];
        #pragma unroll
        for (int i = 0; i < 4; i++) {
            a[i] = *(const bf16x8*)&As[(wm * 64 + i * 16 + l16) * 32 + quad * 8];
            b[i] = *(const bf16x8*)&Bs[(wn * 64 + i * 16 + l16) * 32 + quad * 8];
        }
        #pragma unroll
        for (int i = 0; i < 4; i++)
            #pragma unroll
            for (int j = 0; j < 4; j++)
                acc[i][j] = __builtin_amdgcn_mfma_f32_16x16x32_bf16(a[i], b[j], acc[i][j], 0, 0, 0);
    }

    float* oh = out + (size_t)h * T * D;
    #pragma unroll
    for (int i = 0; i < 4; i++) {
        int t_base = bi * 128 + wm * 64 + i * 16 + quad * 4;
        #pragma unroll
        for (int j = 0; j < 4; j++) {
            int d_g = dblk * 128 + wn * 64 + j * 16 + l16;
            #pragma unroll
            for (int r = 0; r < 4; r++) {
                int t_g = t_base + r;
                atomicAdd(&oh[(size_t)t_g * D + d_g], acc[i][j][r]);
            }
        }
    }
}

extern "C" void kernel_launch(void* const* d_in, const int* in_sizes, int n_in,
                              void* d_out, int out_size, void* d_ws, size_t ws_size,
                              hipStream_t stream) {
    const float* Q = (const float*)d_in[0];   // (1, 4, 2048, 8192) fp32
    const float* V = (const float*)d_in[1];   // (1, 1, 2048, 256)  fp32
    float* out = (float*)d_out;               // (1, 4, 2048, 256)  fp32

    const size_t qr_elems = (size_t)NH * T * N;   // 67.1M
    const size_t vt_elems = (size_t)D * T;        // 0.5M
    const size_t s_elems  = (size_t)NH * T * T;   // 16.8M per split

    // choose split factor by available workspace (KS=2 needs ~193 MB, KS=1 ~161 MB)
    int KS = (ws_size >= (qr_elems + vt_elems + 2 * s_elems) * sizeof(unsigned short)) ? 2 : 1;
    if (ws_size < (qr_elems + vt_elems + (size_t)KS * s_elems) * sizeof(unsigned short)) return;

    unsigned short* QR = (unsigned short*)d_ws;
    unsigned short* Vt = QR + qr_elems;
    unsigned short* S  = Vt + vt_elems;   // KS consecutive buffers of s_elems

    rope_kernel<<<(NH * T * N / 4) / 256, 256, 0, stream>>>(Q, QR);
    vt_kernel<<<(T / 64) * (D / 64), 256, 0, stream>>>(V, Vt);
    gemm1_kernel<<<NH * 136 * KS, 256, 0, stream>>>(QR, S, KS);
    hipMemsetAsync(d_out, 0, (size_t)out_size * sizeof(float), stream);
    gemm2_kernel<<<NH * 2 * KS * 40, 256, 0, stream>>>(S, Vt, out, KS);
}

// Round 3
// 605.466 us; speedup vs baseline: 1.0684x; 1.0281x over previous
//
#include <hip/hip_runtime.h>

#define LDS_AS __attribute__((address_space(3)))
#define GLB_AS __attribute__((address_space(1)))

typedef __attribute__((ext_vector_type(8))) short bf16x8;   // 8 bf16 = 4 VGPRs (A/B frag)
typedef __attribute__((ext_vector_type(4))) float f32x4;    // C/D frag

static constexpr int NH = 4;
static constexpr int T  = 2048;
static constexpr int N  = 8192;
static constexpr int D  = 256;

__device__ inline unsigned short f2bf(float f) {
    unsigned int u = __float_as_uint(f);
    u += 0x7FFFu + ((u >> 16) & 1u);   // round-to-nearest-even
    return (unsigned short)(u >> 16);
}

__device__ inline void gl2lds16(const void* g, void* l) {
    __builtin_amdgcn_global_load_lds((GLB_AS void*)g, (LDS_AS void*)l, 16, 0, 0);
}

// ---------------- RoPE + bf16 cast: QR[h][t][n] ----------------
__global__ void rope_kernel(const float* __restrict__ Q, unsigned short* __restrict__ QR) {
    int g = blockIdx.x * 256 + threadIdx.x;     // one thread = 4 consecutive elements
    int base = g << 2;
    int n = base & (N - 1);
    int t = (base >> 13) & (T - 1);
    const float4 q = *(const float4*)(Q + (size_t)base);
    float tf = (float)t;
    const float inv2pi = 0.15915494309189535f;
    float f0 = exp2f((float)n       * (-1.0f / 512.0f)) * inv2pi;
    float f1 = exp2f((float)(n + 2) * (-1.0f / 512.0f)) * inv2pi;
    float r0 = tf * f0; r0 -= floorf(r0);
    float r1 = tf * f1; r1 -= floorf(r1);
    float s0 = __builtin_amdgcn_sinf(r0), c0 = __builtin_amdgcn_cosf(r0);
    float s1 = __builtin_amdgcn_sinf(r1), c1 = __builtin_amdgcn_cosf(r1);
    ushort4 o;
    o.x = f2bf(q.x * c0 - q.y * s0);
    o.y = f2bf(q.y * c0 + q.x * s0);
    o.z = f2bf(q.z * c1 - q.w * s1);
    o.w = f2bf(q.w * c1 + q.z * s1);
    *(ushort4*)(QR + (size_t)base) = o;
}

// ---------------- V -> Vt bf16 transpose via LDS: Vt[d][t] = bf16(V[t][d]) ----------------
__global__ void vt_kernel(const float* __restrict__ V, unsigned short* __restrict__ Vt) {
    __shared__ unsigned short tile[64 * 65];
    int tb = blockIdx.x >> 2, db = blockIdx.x & 3;
    int t0 = tb * 64, d0 = db * 64;
    int tid = threadIdx.x;
    #pragma unroll
    for (int r = 0; r < 16; r++) {
        int idx = tid + r * 256;
        int tl = idx >> 6, dl = idx & 63;
        tile[tl * 65 + dl] = f2bf(V[(size_t)(t0 + tl) * D + d0 + dl]);
    }
    __syncthreads();
    #pragma unroll
    for (int r = 0; r < 16; r++) {
        int idx = tid + r * 256;
        int dl = idx >> 6, tl = idx & 63;
        Vt[(size_t)(d0 + dl) * T + t0 + tl] = tile[tl * 65 + dl];
    }
}

// ---------------- GEMM1 v3: 128(t) x 256(s) tile, LDS double-buffer, 1 barrier/iter ----
// 4 waves as 2x2; wave tile 64x128 (4 x 8 frags of 16x16). Tasks: bj*256 <= bi*128 region.
__global__ __launch_bounds__(256, 2) void gemm1_kernel(const unsigned short* __restrict__ QR,
                                                       unsigned short* __restrict__ S, int KS) {
    __shared__ __align__(16) unsigned short As[2][128 * 32];   // 8 KB each
    __shared__ __align__(16) unsigned short Bs[2][256 * 32];   // 16 KB each

    int bx = blockIdx.x;
    int per_h = 72 * KS;
    int h = bx / per_h;
    int rem = bx % per_h;
    int task = rem / KS;
    int ks = rem % KS;
    // decode (bi, bj): bj in [0, bi/2]; counts 1,1,2,2,...,8,8 sum=72
    int bi = 0, cum = 0;
    for (; bi < 16; bi++) { int nb = (bi >> 1) + 1; if (cum + nb > task) break; cum += nb; }
    int bj = task - cum;

    const unsigned short* A = QR + (size_t)h * T * N + (size_t)bi * 128 * N;
    const unsigned short* B = QR + (size_t)h * T * N + (size_t)bj * 256 * N;

    int KN = N / KS;
    int k_begin = ks * KN;
    int nit = KN / 32;

    int tid = threadIdx.x;
    int lane = tid & 63, wave = tid >> 6;
    int wm = wave >> 1, wn = wave & 1;
    int quad = lane >> 4, l16 = lane & 15;
    int srow = tid >> 2;
    int scol = (tid & 3) * 8;

    f32x4 acc[4][8];
    #pragma unroll
    for (int i = 0; i < 4; i++)
        #pragma unroll
        for (int j = 0; j < 8; j++)
            #pragma unroll
            for (int r = 0; r < 4; r++) acc[i][j][r] = 0.0f;

    // preloop stage into buffer 0
    {
        int k0 = k_begin;
        gl2lds16(A + (size_t)srow * N + k0 + scol,         &As[0][srow * 32 + scol]);
        gl2lds16(A + (size_t)(srow + 64) * N + k0 + scol,  &As[0][(srow + 64) * 32 + scol]);
        gl2lds16(B + (size_t)srow * N + k0 + scol,         &Bs[0][srow * 32 + scol]);
        gl2lds16(B + (size_t)(srow + 64) * N + k0 + scol,  &Bs[0][(srow + 64) * 32 + scol]);
        gl2lds16(B + (size_t)(srow + 128) * N + k0 + scol, &Bs[0][(srow + 128) * 32 + scol]);
        gl2lds16(B + (size_t)(srow + 192) * N + k0 + scol, &Bs[0][(srow + 192) * 32 + scol]);
    }

    for (int it = 0; it < nit; it++) {
        int cur = it & 1, nxt = cur ^ 1;
        __syncthreads();   // drains vmcnt: cur's stage was issued a full iteration ago
        if (it + 1 < nit) {
            int k0 = k_begin + (it + 1) * 32;
            gl2lds16(A + (size_t)srow * N + k0 + scol,         &As[nxt][srow * 32 + scol]);
            gl2lds16(A + (size_t)(srow + 64) * N + k0 + scol,  &As[nxt][(srow + 64) * 32 + scol]);
            gl2lds16(B + (size_t)srow * N + k0 + scol,         &Bs[nxt][srow * 32 + scol]);
            gl2lds16(B + (size_t)(srow + 64) * N + k0 + scol,  &Bs[nxt][(srow + 64) * 32 + scol]);
            gl2lds16(B + (size_t)(srow + 128) * N + k0 + scol, &Bs[nxt][(srow + 128) * 32 + scol]);
            gl2lds16(B + (size_t)(srow + 192) * N + k0 + scol, &Bs[nxt][(srow + 192) * 32 + scol]);
        }

        bf16x8 a[4];
        #pragma unroll
        for (int i = 0; i < 4; i++)
            a[i] = *(const bf16x8*)&As[cur][(wm * 64 + i * 16 + l16) * 32 + quad * 8];
        #pragma unroll
        for (int j = 0; j < 8; j++) {
            bf16x8 b = *(const bf16x8*)&Bs[cur][(wn * 128 + j * 16 + l16) * 32 + quad * 8];
            #pragma unroll
            for (int i = 0; i < 4; i++)
                acc[i][j] = __builtin_amdgcn_mfma_f32_16x16x32_bf16(a[i], b, acc[i][j], 0, 0, 0);
        }
    }

    // epilogue: C/D layout col = lane&15, row = quad*4 + r; strictly-lower mask s < t
    unsigned short* Sh = S + (size_t)ks * NH * T * T + (size_t)h * T * T;
    #pragma unroll
    for (int i = 0; i < 4; i++) {
        int t_base = bi * 128 + wm * 64 + i * 16 + quad * 4;
        #pragma unroll
        for (int j = 0; j < 8; j++) {
            int s_g = bj * 256 + wn * 128 + j * 16 + l16;
            #pragma unroll
            for (int r = 0; r < 4; r++) {
                int t_g = t_base + r;
                float v = (s_g < t_g) ? acc[i][j][r] : 0.0f;
                Sh[(size_t)t_g * T + s_g] = f2bf(v);
            }
        }
    }
}

// ---------------- GEMM2: out[h] += sum_ks S[ks][h][tile] @ Vt^T over <=512-wide K chunks ----
// grid = NH * 2(dblk) * 40(chunk tasks); ks folded inside; fp32 atomics into zeroed d_out.
__global__ __launch_bounds__(256) void gemm2_kernel(const unsigned short* __restrict__ S,
                                                    const unsigned short* __restrict__ Vt,
                                                    float* __restrict__ out, int KS) {
    __shared__ __align__(16) unsigned short As[128 * 32];
    __shared__ __align__(16) unsigned short Bs[128 * 32];

    int bx = blockIdx.x;
    int per_h = 2 * 40;
    int h = bx / per_h;
    int rem = bx % per_h;
    int dblk = rem / 40;
    int tc = rem % 40;
    // decode (bi, chunk): nc(bi) = ceil((bi+1)/4), sum = 40
    int bi = 0, cum = 0;
    for (; bi < 16; bi++) { int nc = (bi + 4) >> 2; if (cum + nc > tc) break; cum += nc; }
    int c = tc - cum;

    int kend = (bi + 1) * 128;
    int cstart = c * 512;
    int clen = min(512, kend - cstart);   // multiple of 128

    const unsigned short* B = Vt + (size_t)dblk * 128 * T + cstart;

    int tid = threadIdx.x;
    int lane = tid & 63, wave = tid >> 6;
    int wm = wave >> 1, wn = wave & 1;
    int quad = lane >> 4, l16 = lane & 15;
    int srow = tid >> 2;
    int scol = (tid & 3) * 8;

    f32x4 acc[4][4];
    #pragma unroll
    for (int i = 0; i < 4; i++)
        #pragma unroll
        for (int j = 0; j < 4; j++)
            #pragma unroll
            for (int r = 0; r < 4; r++) acc[i][j][r] = 0.0f;

    for (int ks = 0; ks < KS; ks++) {
        const unsigned short* A = S + (size_t)ks * NH * T * T + (size_t)h * T * T
                                    + (size_t)bi * 128 * T + cstart;
        for (int k0 = 0; k0 < clen; k0 += 32) {
            __syncthreads();
            gl2lds16(A + (size_t)srow * T + k0 + scol,        &As[srow * 32 + scol]);
            gl2lds16(A + (size_t)(srow + 64) * T + k0 + scol, &As[(srow + 64) * 32 + scol]);
            gl2lds16(B + (size_t)srow * T + k0 + scol,        &Bs[srow * 32 + scol]);
            gl2lds16(B + (size_t)(srow + 64) * T + k0 + scol, &Bs[(srow + 64) * 32 + scol]);
            __syncthreads();

            bf16x8 a[4], b[4];
            #pragma unroll
            for (int i = 0; i < 4; i++) {
                a[i] = *(const bf16x8*)&As[(wm * 64 + i * 16 + l16) * 32 + quad * 8];
                b[i] = *(const bf16x8*)&Bs[(wn * 64 + i * 16 + l16) * 32 + quad * 8];
            }
            #pragma unroll
            for (int i = 0; i < 4; i++)
                #pragma unroll
                for (int j = 0; j < 4; j++)
                    acc[i][j] = __builtin_amdgcn_mfma_f32_16x16x32_bf16(a[i], b[j], acc[i][j], 0, 0, 0);
        }
    }

    float* oh = out + (size_t)h * T * D;
    #pragma unroll
    for (int i = 0; i < 4; i++) {
        int t_base = bi * 128 + wm * 64 + i * 16 + quad * 4;
        #pragma unroll
        for (int j = 0; j < 4; j++) {
            int d_g = dblk * 128 + wn * 64 + j * 16 + l16;
            #pragma unroll
            for (int r = 0; r < 4; r++) {
                int t_g = t_base + r;
                atomicAdd(&oh[(size_t)t_g * D + d_g], acc[i][j][r]);
            }
        }
    }
}

extern "C" void kernel_launch(void* const* d_in, const int* in_sizes, int n_in,
                              void* d_out, int out_size, void* d_ws, size_t ws_size,
                              hipStream_t stream) {
    const float* Q = (const float*)d_in[0];   // (1, 4, 2048, 8192) fp32
    const float* V = (const float*)d_in[1];   // (1, 1, 2048, 256)  fp32
    float* out = (float*)d_out;               // (1, 4, 2048, 256)  fp32

    const size_t qr_elems = (size_t)NH * T * N;   // 67.1M
    const size_t vt_elems = (size_t)D * T;        // 0.5M
    const size_t s_elems  = (size_t)NH * T * T;   // 16.8M per split

    // largest KS in {4,2,1} that fits (KS must divide N/32 -> powers of 2)
    int KS = 1;
    for (int cand : {4, 2, 1}) {
        if (ws_size >= (qr_elems + vt_elems + (size_t)cand * s_elems) * sizeof(unsigned short)) {
            KS = cand; break;
        }
    }
    if (ws_size < (qr_elems + vt_elems + (size_t)KS * s_elems) * sizeof(unsigned short)) return;

    unsigned short* QR = (unsigned short*)d_ws;
    unsigned short* Vt = QR + qr_elems;
    unsigned short* S  = Vt + vt_elems;   // KS consecutive buffers of s_elems

    rope_kernel<<<(NH * T * N / 4) / 256, 256, 0, stream>>>(Q, QR);
    vt_kernel<<<(T / 64) * (D / 64), 256, 0, stream>>>(V, Vt);
    gemm1_kernel<<<NH * 72 * KS, 256, 0, stream>>>(QR, S, KS);
    hipMemsetAsync(d_out, 0, (size_t)out_size * sizeof(float), stream);
    gemm2_kernel<<<NH * 2 * 40, 256, 0, stream>>>(S, Vt, out, KS);
}